// Round 2
// baseline (355.245 us; speedup 1.0000x reference)
//
#include <hip/hip_runtime.h>

// y[b,s,f] = init[b] + FACTOR * cumsum_s(x)[b,s,f]
// B=1024, S=4096, F=11, fp32. Pure streaming scan, memory-bound.
//
// Structure: 1 block per batch row, 1024 blocks x 256 threads.
// TS=512-timestep tiles (8 tiles/row), staged via 22.5 KB LDS so that
// exactly 4 blocks/CU are resident in ONE round (grid 1024 = 256 CU x 4).
// Per tile: coalesced float4 load -> LDS -> per-thread 2-step local scan
// (float2 reads, 2-way banks = free) -> wave shuffle-scan -> cross-wave
// combine -> write back -> coalesced float4 store.

#define BATCH    1024
#define SEQ      4096
#define FEAT     11
#define FACTOR   (-1.0f)

#define NTHREADS 256
#define TS       512                     // timesteps per tile
#define NT       (SEQ / TS)              // 8 tiles
#define CPT      (TS / NTHREADS)         // 2 timesteps per thread
#define TILE_FLOATS (TS * FEAT)          // 5632
#define TILE_F4  (TILE_FLOATS / 4)       // 1408 float4 per tile
#define VLMAX    ((TILE_F4 + NTHREADS - 1) / NTHREADS)  // 6 (ragged: last is half)

__global__ __launch_bounds__(NTHREADS, 4)
void rnn_scan_kernel(const float* __restrict__ x,
                     const float* __restrict__ init_state,
                     float* __restrict__ y) {
    __shared__ float4 tile_lds[TILE_F4];     // 22,528 B
    __shared__ float  waveTot[4][FEAT];      // 176 B

    const int b    = blockIdx.x;
    const int t    = threadIdx.x;
    const int lane = t & 63;
    const int wav  = t >> 6;

    const float4* __restrict__ xg =
        (const float4*)(x + (size_t)b * (SEQ * FEAT));
    float4* __restrict__ yg =
        (float4*)(y + (size_t)b * (SEQ * FEAT));
    const float init_v = init_state[b];

    float carry[FEAT];
#pragma unroll
    for (int f = 0; f < FEAT; ++f) carry[f] = 0.0f;

    // Prologue: load tile 0 (ragged: 1408 f4 over 256 threads = 5.5/thread)
    float4 cur[VLMAX];
#pragma unroll
    for (int i = 0; i < VLMAX; ++i) {
        int idx = t + NTHREADS * i;
        if (idx < TILE_F4) cur[i] = xg[idx];
    }

#pragma unroll
    for (int tile = 0; tile < NT; ++tile) {
        // ---- Phase A: stage x tile to LDS (linear float4 layout) ----
#pragma unroll
        for (int i = 0; i < VLMAX; ++i) {
            int idx = t + NTHREADS * i;
            if (idx < TILE_F4) tile_lds[idx] = cur[i];
        }
        __syncthreads();

        // Prefetch next tile (latency hidden under scan phases)
        if (tile + 1 < NT) {
#pragma unroll
            for (int i = 0; i < VLMAX; ++i) {
                int idx = t + NTHREADS * i;
                if (idx < TILE_F4) cur[i] = xg[(tile + 1) * TILE_F4 + idx];
            }
        }

        // ---- Phase B: own 2 consecutive timesteps (22 floats) ----
        // float2 index 11t+m -> word 22t+2m: bank stride 22 (gcd(22,32)=2)
        // => 2 lanes/bank within a phase = conflict-free.
        const float2* lds2 = (const float2*)tile_lds;
        float L[2 * FEAT];
#pragma unroll
        for (int m = 0; m < FEAT; ++m) {
            float2 q = lds2[FEAT * t + m];
            L[2 * m]     = q.x;
            L[2 * m + 1] = q.y;
        }
        // local inclusive prefix over the 2 timesteps, per feature
        float inc[FEAT];
#pragma unroll
        for (int f = 0; f < FEAT; ++f) {
            L[FEAT + f] += L[f];
            inc[f] = L[FEAT + f];
        }
        // wave-level inclusive scan of per-thread totals
#pragma unroll
        for (int d = 1; d < 64; d <<= 1) {
#pragma unroll
            for (int f = 0; f < FEAT; ++f) {
                float o = __shfl_up(inc[f], d, 64);
                if (lane >= d) inc[f] += o;
            }
        }
        if (lane == 63) {
#pragma unroll
            for (int f = 0; f < FEAT; ++f) waveTot[wav][f] = inc[f];
        }
        __syncthreads();

        // ---- Phase C: offsets + epilogue, write y back to own LDS slots ----
        float2* lds2w = (float2*)tile_lds;
#pragma unroll
        for (int f = 0; f < FEAT; ++f) {
            float off = carry[f] + inc[f] - L[FEAT + f];  // exclusive in wave
#pragma unroll
            for (int w = 0; w < 4; ++w) {
                float wt = waveTot[w][f];
                if (w < wav) off += wt;    // preceding waves
                carry[f] += wt;            // full-tile total -> next tile
            }
            L[f]        = init_v + FACTOR * (off + L[f]);
            L[FEAT + f] = init_v + FACTOR * (off + L[FEAT + f]);
        }
#pragma unroll
        for (int m = 0; m < FEAT; ++m)
            lds2w[FEAT * t + m] = make_float2(L[2 * m], L[2 * m + 1]);
        __syncthreads();

        // ---- Phase D: coalesced float4 store ----
        // (reads own linear slots; next tile's Phase A rewrites the same
        //  slots from the same thread -> no 4th barrier needed)
#pragma unroll
        for (int i = 0; i < VLMAX; ++i) {
            int idx = t + NTHREADS * i;
            if (idx < TILE_F4) yg[tile * TILE_F4 + idx] = tile_lds[idx];
        }
    }
}

extern "C" void kernel_launch(void* const* d_in, const int* in_sizes, int n_in,
                              void* d_out, int out_size, void* d_ws, size_t ws_size,
                              hipStream_t stream) {
    const float* x    = (const float*)d_in[0];
    const float* init = (const float*)d_in[1];
    float*       y    = (float*)d_out;
    rnn_scan_kernel<<<dim3(BATCH), dim3(NTHREADS), 0, stream>>>(x, init, y);
}